// Round 1
// baseline (468.700 us; speedup 1.0000x reference)
//
#include <hip/hip_runtime.h>

// Problem constants
#define Bv 32
#define Tv 2048
#define Hv 512
#define Dv 1024

// MFMA fragment types (gfx950 mfma_f32_16x16x32_bf16: V8y inputs, V4f acc)
using bf16x8 = __attribute__((ext_vector_type(8))) __bf16;
using f32x4  = __attribute__((ext_vector_type(4))) float;

// ---------------------------------------------------------------------------
// Kernel 1: convert We = W_attn[:, D:2D] to bf16, laid out in MFMA B-fragment
// order: slot s = ((nt*32 + kt)*64 + lane), each slot = 8 consecutive d's.
// b_frag element j: We[h = nt*16 + (lane&15)][d = kt*32 + (lane>>4)*8 + j]
// ---------------------------------------------------------------------------
__global__ void swizzle_we(const float* __restrict__ W, bf16x8* __restrict__ We_sw) {
    int s    = blockIdx.x * 256 + threadIdx.x;   // 0..65535 lane-slots
    int lane = s & 63;
    int kt   = (s >> 6) & 31;
    int nt   = s >> 11;
    int h    = nt * 16 + (lane & 15);
    int d    = kt * 32 + ((lane >> 4) << 3);
    const float* src = W + h * (2 * Dv) + Dv + d;
    float4 f0 = *(const float4*)src;
    float4 f1 = *(const float4*)(src + 4);
    bf16x8 o;
    o[0] = (__bf16)f0.x; o[1] = (__bf16)f0.y; o[2] = (__bf16)f0.z; o[3] = (__bf16)f0.w;
    o[4] = (__bf16)f1.x; o[5] = (__bf16)f1.y; o[6] = (__bf16)f1.z; o[7] = (__bf16)f1.w;
    We_sw[s] = o;
}

// ---------------------------------------------------------------------------
// Kernel 2: hp[b][h] = hidden[b,:] . W_attn[h, 0:D]  + b_attn[h]   (fp32)
// One block per h; thread t owns Wh[h][4t..4t+3]; loop over b.
// ---------------------------------------------------------------------------
__global__ void hid_proj_kernel(const float* __restrict__ hidden,
                                const float* __restrict__ W,
                                const float* __restrict__ b_attn,
                                float* __restrict__ hp) {
    int h   = blockIdx.x;
    int tid = threadIdx.x;           // 256
    float4 wh = ((const float4*)(W + h * (2 * Dv)))[tid];
    __shared__ float red[4];
    int lane = tid & 63, w = tid >> 6;
    for (int b = 0; b < Bv; ++b) {
        float4 x = ((const float4*)(hidden + b * Dv))[tid];
        float p = wh.x * x.x + wh.y * x.y + wh.z * x.z + wh.w * x.w;
#pragma unroll
        for (int m = 1; m < 64; m <<= 1) p += __shfl_xor(p, m);
        if (lane == 0) red[w] = p;
        __syncthreads();
        if (tid == 0) hp[b * Hv + h] = red[0] + red[1] + red[2] + red[3] + b_attn[h];
        __syncthreads();
    }
}

// ---------------------------------------------------------------------------
// Kernel 3: fused  scores[b,t] = sum_h v[h]*tanh( enc[b,t,:].We[h,:] + hp[b,h] )
// Block = 64 rows (one b) x all 512 h. 8 waves, wave w owns cols [64w, 64w+64).
// A (enc) staged fp32->bf16 into LDS in A-fragment order; B read directly from
// the pre-swizzled We_sw (L2-resident). Epilogue: tanh + v-dot + LDS reduce.
// ---------------------------------------------------------------------------
__global__ __launch_bounds__(512) void attn_main(
    const float* __restrict__ enc, const bf16x8* __restrict__ Bg,
    const float* __restrict__ hp, const float* __restrict__ vvec,
    float* __restrict__ scores)
{
    __shared__ bf16x8 As8[512];          // [ (mt*2+ktl)*64 + lane ] -> 8 bf16
    __shared__ float  redbuf[8][64];

    const int tid  = threadIdx.x;
    const int lane = tid & 63;
    const int w    = tid >> 6;           // wave 0..7
    const int row0 = blockIdx.x * 64;    // global bt row
    const int batch = row0 >> 11;        // row0 / T

    // Staging map: thread tid stages LDS slot tid (write at base+tid*16, no
    // bank conflicts): mt = tid>>7, ktl = (tid>>6)&1, lane' = tid&63
    const int srow  = ((tid >> 7) << 4) + (lane & 15);            // row in tile
    const int skloc = (((tid >> 6) & 1) << 5) + ((lane >> 4) << 3); // k in chunk
    const float* gA = enc + (row0 + srow) * Dv + skloc;

    f32x4 acc[4][4];
#pragma unroll
    for (int i = 0; i < 4; ++i)
#pragma unroll
        for (int j = 0; j < 4; ++j)
            acc[i][j] = (f32x4){0.f, 0.f, 0.f, 0.f};

    // prefetch chunk 0
    float4 f0 = *(const float4*)gA;
    float4 f1 = *(const float4*)(gA + 4);

    for (int kc = 0; kc < 16; ++kc) {
        // B fragments for this chunk (global, L2-hit, coalesced 16B/lane)
        bf16x8 bfrag[2][4];
#pragma unroll
        for (int ktl = 0; ktl < 2; ++ktl)
#pragma unroll
            for (int j = 0; j < 4; ++j)
                bfrag[ktl][j] = Bg[((w * 4 + j) * 32 + (kc * 2 + ktl)) * 64 + lane];

        __syncthreads();                 // previous chunk's ds_reads done
        bf16x8 o;
        o[0] = (__bf16)f0.x; o[1] = (__bf16)f0.y; o[2] = (__bf16)f0.z; o[3] = (__bf16)f0.w;
        o[4] = (__bf16)f1.x; o[5] = (__bf16)f1.y; o[6] = (__bf16)f1.z; o[7] = (__bf16)f1.w;
        As8[tid] = o;
        if (kc + 1 < 16) {               // prefetch next chunk's A (overlaps MFMA)
            f0 = *(const float4*)(gA + (kc + 1) * 64);
            f1 = *(const float4*)(gA + (kc + 1) * 64 + 4);
        }
        __syncthreads();

#pragma unroll
        for (int ktl = 0; ktl < 2; ++ktl) {
            bf16x8 a0 = As8[(0 * 2 + ktl) * 64 + lane];
            bf16x8 a1 = As8[(1 * 2 + ktl) * 64 + lane];
            bf16x8 a2 = As8[(2 * 2 + ktl) * 64 + lane];
            bf16x8 a3 = As8[(3 * 2 + ktl) * 64 + lane];
#pragma unroll
            for (int j = 0; j < 4; ++j) {
                acc[0][j] = __builtin_amdgcn_mfma_f32_16x16x32_bf16(a0, bfrag[ktl][j], acc[0][j], 0, 0, 0);
                acc[1][j] = __builtin_amdgcn_mfma_f32_16x16x32_bf16(a1, bfrag[ktl][j], acc[1][j], 0, 0, 0);
                acc[2][j] = __builtin_amdgcn_mfma_f32_16x16x32_bf16(a2, bfrag[ktl][j], acc[2][j], 0, 0, 0);
                acc[3][j] = __builtin_amdgcn_mfma_f32_16x16x32_bf16(a3, bfrag[ktl][j], acc[3][j], 0, 0, 0);
            }
        }
    }

    // Epilogue. C/D layout (verified m89/m91): col = lane&15, row = (lane>>4)*4 + reg
    float hpv[4], vv[4];
#pragma unroll
    for (int j = 0; j < 4; ++j) {
        int n  = w * 64 + j * 16 + (lane & 15);
        hpv[j] = hp[batch * Hv + n];
        vv[j]  = vvec[n];
    }
    const int qrow = (lane >> 4) * 4;
#pragma unroll
    for (int mt = 0; mt < 4; ++mt)
#pragma unroll
        for (int r = 0; r < 4; ++r) {
            float p = 0.f;
#pragma unroll
            for (int j = 0; j < 4; ++j)
                p += vv[j] * tanhf(acc[mt][j][r] + hpv[j]);
            // reduce over the 16 columns held by lanes sharing this row
            p += __shfl_xor(p, 1);
            p += __shfl_xor(p, 2);
            p += __shfl_xor(p, 4);
            p += __shfl_xor(p, 8);
            if ((lane & 15) == 0)
                redbuf[w][mt * 16 + qrow + r] = p;
        }
    __syncthreads();
    if (tid < 64) {
        float s = 0.f;
#pragma unroll
        for (int ww = 0; ww < 8; ++ww) s += redbuf[ww][tid];
        scores[row0 + tid] = s;
    }
}

// ---------------------------------------------------------------------------
// Kernel 4: softmax over T per batch row (fp32)
// ---------------------------------------------------------------------------
__global__ void softmax_kernel(const float* __restrict__ scores, float* __restrict__ out) {
    int b   = blockIdx.x;
    int tid = threadIdx.x;               // 256
    const float* s = scores + b * Tv;
    float local[8];
    float m = -1e30f;
#pragma unroll
    for (int i = 0; i < 8; ++i) { local[i] = s[tid + i * 256]; m = fmaxf(m, local[i]); }
    __shared__ float red[4];
    int lane = tid & 63, w = tid >> 6;
#pragma unroll
    for (int x = 1; x < 64; x <<= 1) m = fmaxf(m, __shfl_xor(m, x));
    if (lane == 0) red[w] = m;
    __syncthreads();
    m = fmaxf(fmaxf(red[0], red[1]), fmaxf(red[2], red[3]));
    float sum = 0.f;
#pragma unroll
    for (int i = 0; i < 8; ++i) { local[i] = expf(local[i] - m); sum += local[i]; }
#pragma unroll
    for (int x = 1; x < 64; x <<= 1) sum += __shfl_xor(sum, x);
    __syncthreads();
    if (lane == 0) red[w] = sum;
    __syncthreads();
    sum = red[0] + red[1] + red[2] + red[3];
    float inv = 1.0f / sum;
#pragma unroll
    for (int i = 0; i < 8; ++i) out[b * Tv + tid + i * 256] = local[i] * inv;
}

// ---------------------------------------------------------------------------
extern "C" void kernel_launch(void* const* d_in, const int* in_sizes, int n_in,
                              void* d_out, int out_size, void* d_ws, size_t ws_size,
                              hipStream_t stream) {
    const float* hidden = (const float*)d_in[0];   // (32, 1024)
    const float* enc    = (const float*)d_in[1];   // (32, 2048, 1024)
    const float* W      = (const float*)d_in[2];   // (512, 2048)
    const float* b_attn = (const float*)d_in[3];   // (512,)
    const float* v      = (const float*)d_in[4];   // (512,)
    float* out = (float*)d_out;                    // (32, 1, 2048) fp32

    char* ws = (char*)d_ws;
    bf16x8* We_sw = (bf16x8*)ws;                         // 1 MB  (H*D bf16, swizzled)
    float*  hp    = (float*)(ws + (1 << 20));            // 64 KB (B*H fp32)
    float*  sc    = (float*)(ws + (1 << 20) + (1 << 16)); // 256 KB (B*T fp32)

    swizzle_we<<<256, 256, 0, stream>>>(W, We_sw);
    hid_proj_kernel<<<Hv, 256, 0, stream>>>(hidden, W, b_attn, hp);
    attn_main<<<(Bv * Tv) / 64, 512, 0, stream>>>(enc, We_sw, hp, v, sc);
    softmax_kernel<<<Bv, 256, 0, stream>>>(sc, out);
}

// Round 2
// 443.205 us; speedup vs baseline: 1.0575x; 1.0575x over previous
//
#include <hip/hip_runtime.h>

// Problem constants
#define Bv 32
#define Tv 2048
#define Hv 512
#define Dv 1024

using bf16x8 = __attribute__((ext_vector_type(8))) __bf16;
using bf16x4 = __attribute__((ext_vector_type(4))) __bf16;
using f32x4  = __attribute__((ext_vector_type(4))) float;

// ---------------------------------------------------------------------------
// Kernel 1: We = W_attn[:, D:2D] -> bf16 in MFMA B-fragment order.
// Slot s = ((nt*32+kt)*64 + lane); b_frag elem j = We[nt*16+(lane&15)][kt*32+(lane>>4)*8+j]
// Coalesced reads: consecutive threads read consecutive d within an h row.
// ---------------------------------------------------------------------------
__global__ void swizzle_we(const float* __restrict__ W, bf16x8* __restrict__ We_sw) {
    int g = blockIdx.x * 256 + threadIdx.x;   // 0..65535
    int h = g >> 7;                           // 512 rows
    int d = (g & 127) * 8;                    // 8 consecutive d's
    const float* src = W + h * (2 * Dv) + Dv + d;
    float4 f0 = *(const float4*)src;
    float4 f1 = *(const float4*)(src + 4);
    bf16x8 o;
    o[0] = (__bf16)f0.x; o[1] = (__bf16)f0.y; o[2] = (__bf16)f0.z; o[3] = (__bf16)f0.w;
    o[4] = (__bf16)f1.x; o[5] = (__bf16)f1.y; o[6] = (__bf16)f1.z; o[7] = (__bf16)f1.w;
    int s = ((h >> 4) * 32 + (d >> 5)) * 64 + (((d >> 3) & 3) << 4) + (h & 15);
    We_sw[s] = o;
}

// ---------------------------------------------------------------------------
// Kernel 2: hp[b][h] = hidden[b,:] . W_attn[h,0:D] + b_attn[h]  (fp32)
// Barrier-free inner loop: per-wave shfl reduce, one sync at the end.
// ---------------------------------------------------------------------------
__global__ void hid_proj_kernel(const float* __restrict__ hidden,
                                const float* __restrict__ W,
                                const float* __restrict__ b_attn,
                                float* __restrict__ hp) {
    int h   = blockIdx.x;
    int tid = threadIdx.x;           // 256
    float4 wh = ((const float4*)(W + h * (2 * Dv)))[tid];
    __shared__ float red[4][Bv];
    int lane = tid & 63, w = tid >> 6;
    for (int b = 0; b < Bv; ++b) {
        float4 x = ((const float4*)(hidden + b * Dv))[tid];
        float p = wh.x * x.x + wh.y * x.y + wh.z * x.z + wh.w * x.w;
#pragma unroll
        for (int m = 1; m < 64; m <<= 1) p += __shfl_xor(p, m);
        if (lane == 0) red[w][b] = p;
    }
    __syncthreads();
    if (tid < Bv)
        hp[tid * Hv + h] = red[0][tid] + red[1][tid] + red[2][tid] + red[3][tid] + b_attn[h];
}

__device__ __forceinline__ float fast_tanh(float x) {
    float xc = fminf(fmaxf(x, -9.0f), 9.0f);
    float e  = __expf(2.0f * xc);
    return 1.0f - 2.0f / (e + 1.0f);
}

// ---------------------------------------------------------------------------
// Kernel 3: scores[b,t] = sum_h v[h]*tanh( enc[b,t,:].We[h,:] + hp[b,h] )
// Block = 64 rows x 512 h, 8 waves. Row-major padded LDS A-tile (72 bf16 row
// stride -> 16B-aligned b128, conflict-free both sides), double-buffered with
// ONE barrier per chunk, B fragments register-prefetched one chunk ahead.
// ---------------------------------------------------------------------------
__global__ __launch_bounds__(512) void attn_main(
    const float* __restrict__ enc, const bf16x8* __restrict__ Bg,
    const float* __restrict__ hp, const float* __restrict__ vvec,
    float* __restrict__ scores)
{
    __shared__ __align__(16) __bf16 Abuf[2][64 * 72];  // 2 x 9216 B
    __shared__ float redbuf[8][64];

    const int tid   = threadIdx.x;
    const int lane  = tid & 63;
    const int w     = tid >> 6;          // wave 0..7
    const int row0  = blockIdx.x * 64;
    const int batch = row0 >> 11;

    // --- A staging map (coalesced): thread -> (row = tid>>3, d segs (tid&7)*4 and +32)
    const int srow = tid >> 3;           // 0..63
    const int sd0  = (tid & 7) * 4;      // 0,4,..,28
    const float* gA = enc + (row0 + srow) * Dv + sd0;
    __bf16* lw0 = &Abuf[0][srow * 72 + sd0];

    // --- B fragment base: frag(j,ktl,kc) at Bg[((w*4+j)*32 + kc*2+ktl)*64 + lane]
    const bf16x8* Bptr = Bg + (w * 4 * 32) * 64 + lane;

    f32x4 acc[4][4];
#pragma unroll
    for (int i = 0; i < 4; ++i)
#pragma unroll
        for (int j = 0; j < 4; ++j)
            acc[i][j] = (f32x4){0.f, 0.f, 0.f, 0.f};

    // prologue: A(0) and B(0) prefetch
    float4 f0 = *(const float4*)gA;
    float4 f1 = *(const float4*)(gA + 32);
    bf16x8 Bc[2][4];
#pragma unroll
    for (int ktl = 0; ktl < 2; ++ktl)
#pragma unroll
        for (int j = 0; j < 4; ++j)
            Bc[ktl][j] = Bptr[(j * 32 + ktl) * 64];

    const int arow  = lane & 15;
    const int acol8 = (lane >> 4) * 8;

    for (int kc = 0; kc < 16; ++kc) {
        // convert + store A(kc) into buf kc&1 (conflict-free ds_write_b64 x2)
        __bf16* p = lw0 + (kc & 1) * (64 * 72);
        bf16x4 o0, o1;
        o0[0] = (__bf16)f0.x; o0[1] = (__bf16)f0.y; o0[2] = (__bf16)f0.z; o0[3] = (__bf16)f0.w;
        o1[0] = (__bf16)f1.x; o1[1] = (__bf16)f1.y; o1[2] = (__bf16)f1.z; o1[3] = (__bf16)f1.w;
        *(bf16x4*)p        = o0;
        *(bf16x4*)(p + 32) = o1;
        // issue A(kc+1) (full-chunk latency budget)
        if (kc < 15) {
            f0 = *(const float4*)(gA + (kc + 1) * 64);
            f1 = *(const float4*)(gA + (kc + 1) * 64 + 32);
        }
        __syncthreads();

        // issue B(kc+1) prefetch (hidden under this chunk's MFMAs)
        bf16x8 Bn[2][4];
        if (kc < 15) {
#pragma unroll
            for (int ktl = 0; ktl < 2; ++ktl)
#pragma unroll
                for (int j = 0; j < 4; ++j)
                    Bn[ktl][j] = Bptr[(j * 32 + (kc + 1) * 2 + ktl) * 64];
        }

        const __bf16* rb = &Abuf[kc & 1][0];
#pragma unroll
        for (int ktl = 0; ktl < 2; ++ktl) {
            bf16x8 a0 = *(const bf16x8*)(rb + (0 * 16 + arow) * 72 + ktl * 32 + acol8);
            bf16x8 a1 = *(const bf16x8*)(rb + (1 * 16 + arow) * 72 + ktl * 32 + acol8);
            bf16x8 a2 = *(const bf16x8*)(rb + (2 * 16 + arow) * 72 + ktl * 32 + acol8);
            bf16x8 a3 = *(const bf16x8*)(rb + (3 * 16 + arow) * 72 + ktl * 32 + acol8);
#pragma unroll
            for (int j = 0; j < 4; ++j) {
                acc[0][j] = __builtin_amdgcn_mfma_f32_16x16x32_bf16(a0, Bc[ktl][j], acc[0][j], 0, 0, 0);
                acc[1][j] = __builtin_amdgcn_mfma_f32_16x16x32_bf16(a1, Bc[ktl][j], acc[1][j], 0, 0, 0);
                acc[2][j] = __builtin_amdgcn_mfma_f32_16x16x32_bf16(a2, Bc[ktl][j], acc[2][j], 0, 0, 0);
                acc[3][j] = __builtin_amdgcn_mfma_f32_16x16x32_bf16(a3, Bc[ktl][j], acc[3][j], 0, 0, 0);
            }
        }
#pragma unroll
        for (int ktl = 0; ktl < 2; ++ktl)
#pragma unroll
            for (int j = 0; j < 4; ++j)
                Bc[ktl][j] = Bn[ktl][j];
    }

    // Epilogue. C/D layout: col = lane&15, row = (lane>>4)*4 + reg
    float hpv[4], vv[4];
#pragma unroll
    for (int j = 0; j < 4; ++j) {
        int n  = w * 64 + j * 16 + (lane & 15);
        hpv[j] = hp[batch * Hv + n];
        vv[j]  = vvec[n];
    }
    const int qrow = (lane >> 4) * 4;
#pragma unroll
    for (int mt = 0; mt < 4; ++mt)
#pragma unroll
        for (int r = 0; r < 4; ++r) {
            float p = 0.f;
#pragma unroll
            for (int j = 0; j < 4; ++j)
                p += vv[j] * fast_tanh(acc[mt][j][r] + hpv[j]);
            p += __shfl_xor(p, 1);
            p += __shfl_xor(p, 2);
            p += __shfl_xor(p, 4);
            p += __shfl_xor(p, 8);
            if ((lane & 15) == 0)
                redbuf[w][mt * 16 + qrow + r] = p;
        }
    __syncthreads();
    if (tid < 64) {
        float s = 0.f;
#pragma unroll
        for (int ww = 0; ww < 8; ++ww) s += redbuf[ww][tid];
        scores[row0 + tid] = s;
    }
}

// ---------------------------------------------------------------------------
// Kernel 4: softmax over T per batch row (fp32)
// ---------------------------------------------------------------------------
__global__ void softmax_kernel(const float* __restrict__ scores, float* __restrict__ out) {
    int b   = blockIdx.x;
    int tid = threadIdx.x;               // 256
    const float* s = scores + b * Tv;
    float local[8];
    float m = -1e30f;
#pragma unroll
    for (int i = 0; i < 8; ++i) { local[i] = s[tid + i * 256]; m = fmaxf(m, local[i]); }
    __shared__ float red[4];
    int lane = tid & 63, w = tid >> 6;
#pragma unroll
    for (int x = 1; x < 64; x <<= 1) m = fmaxf(m, __shfl_xor(m, x));
    if (lane == 0) red[w] = m;
    __syncthreads();
    m = fmaxf(fmaxf(red[0], red[1]), fmaxf(red[2], red[3]));
    float sum = 0.f;
#pragma unroll
    for (int i = 0; i < 8; ++i) { local[i] = expf(local[i] - m); sum += local[i]; }
#pragma unroll
    for (int x = 1; x < 64; x <<= 1) sum += __shfl_xor(sum, x);
    __syncthreads();
    if (lane == 0) red[w] = sum;
    __syncthreads();
    sum = red[0] + red[1] + red[2] + red[3];
    float inv = 1.0f / sum;
#pragma unroll
    for (int i = 0; i < 8; ++i) out[b * Tv + tid + i * 256] = local[i] * inv;
}

// ---------------------------------------------------------------------------
extern "C" void kernel_launch(void* const* d_in, const int* in_sizes, int n_in,
                              void* d_out, int out_size, void* d_ws, size_t ws_size,
                              hipStream_t stream) {
    const float* hidden = (const float*)d_in[0];   // (32, 1024)
    const float* enc    = (const float*)d_in[1];   // (32, 2048, 1024)
    const float* W      = (const float*)d_in[2];   // (512, 2048)
    const float* b_attn = (const float*)d_in[3];   // (512,)
    const float* v      = (const float*)d_in[4];   // (512,)
    float* out = (float*)d_out;                    // (32, 1, 2048) fp32

    char* ws = (char*)d_ws;
    bf16x8* We_sw = (bf16x8*)ws;                          // 1 MB
    float*  hp    = (float*)(ws + (1 << 20));             // 64 KB
    float*  sc    = (float*)(ws + (1 << 20) + (1 << 16)); // 256 KB

    swizzle_we<<<256, 256, 0, stream>>>(W, We_sw);
    hid_proj_kernel<<<Hv, 256, 0, stream>>>(hidden, W, b_attn, hp);
    attn_main<<<(Bv * Tv) / 64, 512, 0, stream>>>(enc, We_sw, hp, v, sc);
    softmax_kernel<<<Bv, 256, 0, stream>>>(sc, out);
}